// Round 1
// baseline (187.978 us; speedup 1.0000x reference)
//
#include <hip/hip_runtime.h>
#include <math.h>

// CTC batch cost (keras.backend.ctc_batch_cost semantics, full lengths).
// B=512 batch, T=512 time, C=96 classes (blank=95), L=64 labels, S=2L+1=129.
//
// Strategy: one 64-lane wave per batch item (wave-synchronous, no barriers).
// Linear-domain forward recurrence with periodic exact power-of-2 rescaling
// (no transcendentals in the hot loop). Lane l owns extended states 2l
// (blank) and 2l+1 (label l); lane 63 additionally owns state 128 (blank).
// Only alpha[2l-1] is ever needed from the neighbor lane -> one ds_bpermute
// per time step. Prefetch ring of 16 steps hides HBM latency.

constexpr int Bv = 512;
constexpr int Tv = 512;
constexpr int Cv = 96;
constexpr int Lv = 64;
constexpr int BLANK = Cv - 1;       // 95
constexpr float EPSf = 1e-7f;       // keras epsilon

__device__ __forceinline__ float bperm_up(int addr, float x) {
    // lane l reads lane (addr/4); addr precomputed as 4*(l-1)
    return __int_as_float(__builtin_amdgcn_ds_bpermute(addr, __float_as_int(x)));
}

__global__ void __launch_bounds__(64) ctc_fwd(const int* __restrict__ y_true,
                                              const float* __restrict__ y_pred,
                                              float* __restrict__ out) {
    const int b = blockIdx.x;
    const int l = threadIdx.x;                      // lane 0..63
    const float* __restrict__ yp = y_pred + (size_t)b * (Tv * Cv);

    const int lab    = y_true[b * Lv + l];          // label l (< 95, never blank)
    const int labm1  = __shfl_up(lab, 1);
    const bool skip  = (l > 0) && (lab != labm1);   // skip for odd state 2l+1
    const bool lane0 = (l == 0);
    const int addr_up = (l - 1) * 4;                // bpermute byte addr

    // ---- t = 0 init: alpha0[0]=p(blank), alpha0[1]=p(label0), rest 0 ----
    float a0 = lane0 ? (yp[BLANK] + EPSf) : 0.0f;   // state 2l
    float a1 = lane0 ? (yp[lab]  + EPSf) : 0.0f;    // state 2l+1
    float a2 = 0.0f;                                // state 128 (real on lane 63)
    int   e_acc = 0;                                // accumulated log2 scale

    // ---- prefetch ring: 16 steps ahead ----
    float fb[16], fl[16];
#pragma unroll
    for (int i = 0; i < 16; ++i) {
        int t = 1 + i;
        fb[i] = yp[t * Cv + BLANK];
        fl[i] = yp[t * Cv + lab];
    }

    auto step = [&](int t, int slot) {
        float pb = fb[slot] + EPSf;
        float pl = fl[slot] + EPSf;
        int tp = t + 16;
        tp = (tp > Tv - 1) ? (Tv - 1) : tp;         // clamped (harmless reload)
        fb[slot] = yp[tp * Cv + BLANK];
        fl[slot] = yp[tp * Cv + lab];

        float a1p = bperm_up(addr_up, a1);          // alpha[2l-1] (old)
        a1p = lane0 ? 0.0f : a1p;
        float na0 = (a0 + a1p) * pb;                        // state 2l
        float s1  = a0 + a1 + (skip ? a1p : 0.0f);          // state 2l+1
        float na1 = s1 * pl;
        float na2 = (a2 + a1) * pb;                         // state 128 (lane63)
        a0 = na0; a1 = na1; a2 = na2;
    };

    auto renorm = [&]() {
        float m = fmaxf(fmaxf(a0, a1), a2);
#pragma unroll
        for (int off = 1; off < 64; off <<= 1)
            m = fmaxf(m, __shfl_xor(m, off));
        int e;
        (void)frexpf(m, &e);                        // m = f * 2^e, f in [0.5,1)
        float sc = ldexpf(1.0f, -e);                // exact power-of-2 scale
        a0 *= sc; a1 *= sc; a2 *= sc;
        e_acc += e;
    };

    // ---- main: 31 x 16 steps (t = 1..496), renorm every 8 ----
    int t = 1;
    for (int w = 0; w < 31; ++w) {
#pragma unroll
        for (int i = 0; i < 8; ++i, ++t) step(t, i);
        renorm();
#pragma unroll
        for (int i = 8; i < 16; ++i, ++t) step(t, i);
        renorm();
    }
    // ---- tail: t = 497..504, renorm, t = 505..511 ----
#pragma unroll
    for (int i = 0; i < 8; ++i, ++t) step(t, i);
    renorm();
#pragma unroll
    for (int i = 8; i < 15; ++i, ++t) step(t, i);

    // ---- loss = -logaddexp(alpha[127], alpha[128]) ----
    if (l == 63) {
        float sum = a1 + a2;                        // states 127 + 128
        out[b] = -(logf(sum) + (float)e_acc * 0.69314718055994530942f);
    }
}

extern "C" void kernel_launch(void* const* d_in, const int* in_sizes, int n_in,
                              void* d_out, int out_size, void* d_ws, size_t ws_size,
                              hipStream_t stream) {
    const int*   y_true = (const int*)d_in[0];   // [512, 64] int32
    const float* y_pred = (const float*)d_in[1]; // [512, 512, 96] fp32
    float*       out    = (float*)d_out;         // [512, 1] fp32
    (void)in_sizes; (void)n_in; (void)out_size; (void)d_ws; (void)ws_size;
    ctc_fwd<<<Bv, 64, 0, stream>>>(y_true, y_pred, out);
}

// Round 3
// 164.103 us; speedup vs baseline: 1.1455x; 1.1455x over previous
//
#include <hip/hip_runtime.h>
#include <math.h>

// CTC batch cost (keras.backend.ctc_batch_cost, full lengths).
// B=512, T=512, C=96 (blank=95), L=64, S=2L+1=129.
//
// One 64-lane wave per batch item, wave-synchronous. Linear-domain forward
// recurrence with exact power-of-2 rescaling every 8 steps. Lane l owns
// extended states 2l (blank) and 2l+1 (label l); lane 63 also owns state 128.
//
// Round 3 (= Round 2 intent, compile-fixed): critical path entirely on DPP.
//  - neighbor alpha[2l-1]: DPP wave_shr:1 (VALU, ~4 cyc) instead of ds_bpermute
//  - renorm wave-max: DPP row_shr/row_bcast reduction instead of shfl_xor
//  - dpp ctrl passed as template parameter (builtin requires constant integer)
//  - prefetch ring 24 steps deep to cover HBM latency.

constexpr int Bv = 512;
constexpr int Tv = 512;
constexpr int Cv = 96;
constexpr int Lv = 64;
constexpr int BLANK = Cv - 1;       // 95
constexpr float EPSf = 1e-7f;
constexpr int RING = 24;            // prefetch depth (multiple of 8)

// lane i <- lane i-1 (wave shift right by 1); lane 0 <- 0 (bound_ctrl)
__device__ __forceinline__ float dpp_wave_shr1(float x) {
    return __int_as_float(
        __builtin_amdgcn_update_dpp(0, __float_as_int(x), 0x138, 0xf, 0xf, true));
}

// one DPP-max step; 0-fill on invalid lanes is identity for max of nonnegatives
template <int CTRL>
__device__ __forceinline__ float dpp_maxf(float m) {
    return fmaxf(m, __int_as_float(
        __builtin_amdgcn_update_dpp(0, __float_as_int(m), CTRL, 0xf, 0xf, true)));
}

__global__ void __launch_bounds__(64) ctc_fwd(const int* __restrict__ y_true,
                                              const float* __restrict__ y_pred,
                                              float* __restrict__ out) {
    const int b = blockIdx.x;
    const int l = threadIdx.x;                      // lane 0..63
    const float* __restrict__ yp = y_pred + (size_t)b * (Tv * Cv);

    const int lab   = y_true[b * Lv + l];           // label l (< 95, never blank)
    const int labm1 = __shfl_up(lab, 1);
    const bool skip = (l > 0) && (lab != labm1);    // skip for odd state 2l+1
    const bool lane0 = (l == 0);

    // ---- t = 0 init ----
    float a0 = lane0 ? (yp[BLANK] + EPSf) : 0.0f;   // state 2l
    float a1 = lane0 ? (yp[lab]  + EPSf) : 0.0f;    // state 2l+1
    float a2 = 0.0f;                                // state 128 (real on lane 63)
    int   e_acc = 0;                                // accumulated log2 scale

    // ---- prefetch ring: RING steps ahead ----
    float fb[RING], fl[RING];
#pragma unroll
    for (int i = 0; i < RING; ++i) {
        int t = 1 + i;
        fb[i] = yp[t * Cv + BLANK];
        fl[i] = yp[t * Cv + lab];
    }

    auto step = [&](int t, int slot) {
        float pb = fb[slot] + EPSf;
        float pl = fl[slot] + EPSf;
        int tp = t + RING;
        tp = (tp > Tv - 1) ? (Tv - 1) : tp;         // clamped (harmless reload)
        fb[slot] = yp[tp * Cv + BLANK];
        fl[slot] = yp[tp * Cv + lab];

        float a1p = dpp_wave_shr1(a1);              // alpha[2l-1] (old); lane0 -> 0
        float na0 = (a0 + a1p) * pb;                        // state 2l
        float s1  = a0 + a1 + (skip ? a1p : 0.0f);          // state 2l+1
        float na1 = s1 * pl;
        float na2 = (a2 + a1) * pb;                         // state 128 (lane63)
        a0 = na0; a1 = na1; a2 = na2;
    };

    auto renorm = [&]() {
        float m = fmaxf(fmaxf(a0, a1), a2);
        m = dpp_maxf<0x111>(m);     // row_shr:1
        m = dpp_maxf<0x112>(m);     // row_shr:2
        m = dpp_maxf<0x114>(m);     // row_shr:4
        m = dpp_maxf<0x118>(m);     // row_shr:8   -> lane 15+16k = row max prefix
        m = dpp_maxf<0x142>(m);     // row_bcast:15
        m = dpp_maxf<0x143>(m);     // row_bcast:31 -> lane 63 = full wave max
        float mw = __int_as_float(__builtin_amdgcn_readlane(__float_as_int(m), 63));
        int e;
        (void)frexpf(mw, &e);                       // mw = f * 2^e, f in [0.5,1)
        float sc = ldexpf(1.0f, -e);                // exact power-of-2 scale
        a0 *= sc; a1 *= sc; a2 *= sc;
        e_acc += e;
    };

    // ---- main: 21 blocks x 24 steps (t = 1..504), renorm every 8 ----
    int t = 1;
    for (int w = 0; w < 21; ++w) {
#pragma unroll
        for (int i = 0; i < RING; ++i, ++t) {
            step(t, i);
            if ((i & 7) == 7) renorm();
        }
    }
    // ---- tail: t = 505..511 (slots 0..6) ----
#pragma unroll
    for (int i = 0; i < 7; ++i, ++t) step(t, i);

    // ---- loss = -logaddexp(alpha[127], alpha[128]) ----
    if (l == 63) {
        float sum = a1 + a2;                        // states 127 + 128
        out[b] = -(logf(sum) + (float)e_acc * 0.69314718055994530942f);
    }
}

extern "C" void kernel_launch(void* const* d_in, const int* in_sizes, int n_in,
                              void* d_out, int out_size, void* d_ws, size_t ws_size,
                              hipStream_t stream) {
    const int*   y_true = (const int*)d_in[0];   // [512, 64] int32
    const float* y_pred = (const float*)d_in[1]; // [512, 512, 96] fp32
    float*       out    = (float*)d_out;         // [512, 1] fp32
    (void)in_sizes; (void)n_in; (void)out_size; (void)d_ws; (void)ws_size;
    ctc_fwd<<<Bv, 64, 0, stream>>>(y_true, y_pred, out);
}

// Round 4
// 149.785 us; speedup vs baseline: 1.2550x; 1.0956x over previous
//
#include <hip/hip_runtime.h>
#include <math.h>

// CTC batch cost (keras.backend.ctc_batch_cost, full lengths).
// B=512, T=512, C=96 (blank=95), L=64, S=2L+1=129.
//
// One 64-lane wave per batch item, wave-synchronous (no __syncthreads ever).
// Linear-domain forward recurrence, exact power-of-2 rescale every 8 steps.
// Lane l owns states 2l (blank) and 2l+1 (label l); lane 63 also state 128.
//
// Round 4: memory path restructured.
//  - R1/R3 post-mortem: VGPR_Count=36 proves the fb[]/fl[] prefetch ring was
//    demoted to scratch (32-48 floats can't live in 36 VGPRs) -> every step
//    paid scratch load/store latency. Arrays are banned now.
//  - y_pred rows staged to LDS via global_load_lds width=16, coalesced,
//    double-buffered 32-row chunks (2 x 12 KB), prefetched 2 chunks deep.
//  - chunk boundary uses fine-grained s_waitcnt vmcnt(12) (never drains the
//    in-flight next chunk); single-wave block needs no barrier.
//  - per-step: 2 ds_read (blank=broadcast, label~2-way alias, both free),
//    prefetched 4 rows ahead through NAMED scalar rotation (no arrays).
//  - critical chain stays on DPP VALU: wave_shr:1 + 3 deps ~ 20 cyc/step.

constexpr int Bv = 512;
constexpr int Tv = 512;
constexpr int Cv = 96;
constexpr int Lv = 64;
constexpr int BLANK = Cv - 1;            // 95
constexpr float EPSf = 1e-7f;

constexpr int ROWS = 32;                 // rows per chunk
constexpr int NCHUNK = Tv / ROWS;        // 16
constexpr int CHUNK_FLOATS = ROWS * Cv;  // 3072 floats = 12288 B
constexpr int NLOAD = 12;                // 12288 B / (64 lanes * 16 B)

// lane i <- lane i-1 (wave shift right by 1); lane 0 <- 0 (bound_ctrl)
__device__ __forceinline__ float dpp_wave_shr1(float x) {
    return __int_as_float(
        __builtin_amdgcn_update_dpp(0, __float_as_int(x), 0x138, 0xf, 0xf, true));
}

template <int CTRL>
__device__ __forceinline__ float dpp_maxf(float m) {
    return fmaxf(m, __int_as_float(
        __builtin_amdgcn_update_dpp(0, __float_as_int(m), CTRL, 0xf, 0xf, true)));
}

// async global->LDS: per-lane gptr, wave-uniform LDS base + lane*16 (HW rule)
__device__ __forceinline__ void stage_chunk(const float* g, float* l, int lane) {
#pragma unroll
    for (int j = 0; j < NLOAD; ++j) {
        __builtin_amdgcn_global_load_lds(
            (const __attribute__((address_space(1))) void*)(g + j * 256 + lane * 4),
            (__attribute__((address_space(3))) void*)(l + j * 256),
            16, 0, 0);
    }
}

__global__ void __launch_bounds__(64) ctc_fwd(const int* __restrict__ y_true,
                                              const float* __restrict__ y_pred,
                                              float* __restrict__ out) {
    __shared__ float lds[2 * CHUNK_FLOATS];          // 24 KB

    const int b = blockIdx.x;
    const int l = threadIdx.x;                       // lane 0..63
    const float* __restrict__ yp = y_pred + (size_t)b * (Tv * Cv);

    const int lab   = y_true[b * Lv + l];            // label l (< 95)
    const int labm1 = __shfl_up(lab, 1);
    const bool skip = (l > 0) && (lab != labm1);     // skip for odd state 2l+1
    const bool lane0 = (l == 0);

    // prologue: 2 chunks in flight (24 outstanding vmem)
    stage_chunk(yp, lds, l);
    stage_chunk(yp + CHUNK_FLOATS, lds + CHUNK_FLOATS, l);

    float a0 = 0.0f, a1 = 0.0f, a2 = 0.0f;           // states 2l, 2l+1, 128
    int e_acc = 0;

    // 4-deep named-scalar LDS-read pipeline (NO arrays -> no scratch)
    float pb0, pl0, pb1, pl1, pb2, pl2, pb3, pl3;

    auto preload4 = [&](const float* buf) {
        pb0 = buf[0 * Cv + BLANK]; pl0 = buf[0 * Cv + lab];
        pb1 = buf[1 * Cv + BLANK]; pl1 = buf[1 * Cv + lab];
        pb2 = buf[2 * Cv + BLANK]; pl2 = buf[2 * Cv + lab];
        pb3 = buf[3 * Cv + BLANK]; pl3 = buf[3 * Cv + lab];
    };
    auto rotload = [&](const float* buf, int rn) {
        pb0 = pb1; pl0 = pl1;
        pb1 = pb2; pl1 = pl2;
        pb2 = pb3; pl2 = pl3;
        pb3 = buf[rn * Cv + BLANK]; pl3 = buf[rn * Cv + lab];
    };
    auto step = [&]() {
        float pb = pb0 + EPSf;
        float pl = pl0 + EPSf;
        float a1p = dpp_wave_shr1(a1);               // alpha[2l-1]; lane0 -> 0
        float na0 = (a0 + a1p) * pb;                 // state 2l
        float s1  = a0 + a1 + (skip ? a1p : 0.0f);   // state 2l+1
        float na1 = s1 * pl;
        float na2 = (a2 + a1) * pb;                  // state 128 (lane 63)
        a0 = na0; a1 = na1; a2 = na2;
    };
    auto renorm = [&]() {
        float m = fmaxf(fmaxf(a0, a1), a2);
        m = dpp_maxf<0x111>(m);      // row_shr:1
        m = dpp_maxf<0x112>(m);      // row_shr:2
        m = dpp_maxf<0x114>(m);      // row_shr:4
        m = dpp_maxf<0x118>(m);      // row_shr:8
        m = dpp_maxf<0x142>(m);      // row_bcast:15
        m = dpp_maxf<0x143>(m);      // row_bcast:31 -> lane 63 = wave max
        float mw = __int_as_float(__builtin_amdgcn_readlane(__float_as_int(m), 63));
        int e;
        (void)frexpf(mw, &e);
        float sc = ldexpf(1.0f, -e);                 // exact power-of-2 scale
        a0 *= sc; a1 *= sc; a2 *= sc;
        e_acc += e;
    };

    // ---- chunk 0: wait only its own 12 loads (chunk 1 stays in flight) ----
    __asm__ __volatile__("" ::: "memory");
    __builtin_amdgcn_s_waitcnt(0x0F7C);              // vmcnt(12)
    __asm__ __volatile__("" ::: "memory");
    {
        const float* buf = lds;
        preload4(buf);
        // t = 0 init
        a0 = lane0 ? (pb0 + EPSf) : 0.0f;
        a1 = lane0 ? (pl0 + EPSf) : 0.0f;
        a2 = 0.0f;
        rotload(buf, 4);
#pragma unroll
        for (int r = 1; r < ROWS; ++r) {             // t = 1..31
            step();
            int rn = r + 4; rn = rn > ROWS - 1 ? ROWS - 1 : rn;
            rotload(buf, rn);
            if ((r & 7) == 0) renorm();              // after t = 8, 16, 24
        }
    }
    stage_chunk(yp + 2 * CHUNK_FLOATS, lds, l);      // chunk 2 -> buf0

    // ---- chunks 1..15 ----
    for (int c = 1; c < NCHUNK; ++c) {
        __asm__ __volatile__("" ::: "memory");
        if (c == NCHUNK - 1) __builtin_amdgcn_s_waitcnt(0x0F70);  // vmcnt(0)
        else                 __builtin_amdgcn_s_waitcnt(0x0F7C);  // vmcnt(12)
        __asm__ __volatile__("" ::: "memory");

        const float* buf = lds + (c & 1) * CHUNK_FLOATS;
        preload4(buf);
#pragma unroll
        for (int r = 0; r < ROWS; ++r) {             // t = 32c + r
            step();
            int rn = r + 4; rn = rn > ROWS - 1 ? ROWS - 1 : rn;
            rotload(buf, rn);
            if ((r & 7) == 0) renorm();              // after every t % 8 == 0
        }
        if (c + 2 < NCHUNK)
            stage_chunk(yp + (c + 2) * CHUNK_FLOATS,
                        lds + (c & 1) * CHUNK_FLOATS, l);
    }

    // ---- loss = -logaddexp(alpha[127], alpha[128]) ----
    if (l == 63) {
        float sum = a1 + a2;                         // states 127 + 128
        out[b] = -(logf(sum) + (float)e_acc * 0.69314718055994530942f);
    }
}

extern "C" void kernel_launch(void* const* d_in, const int* in_sizes, int n_in,
                              void* d_out, int out_size, void* d_ws, size_t ws_size,
                              hipStream_t stream) {
    const int*   y_true = (const int*)d_in[0];   // [512, 64] int32
    const float* y_pred = (const float*)d_in[1]; // [512, 512, 96] fp32
    float*       out    = (float*)d_out;         // [512, 1] fp32
    (void)in_sizes; (void)n_in; (void)out_size; (void)d_ws; (void)ws_size;
    ctc_fwd<<<Bv, 64, 0, stream>>>(y_true, y_pred, out);
}

// Round 5
// 148.078 us; speedup vs baseline: 1.2695x; 1.0115x over previous
//
#include <hip/hip_runtime.h>
#include <math.h>

// CTC batch cost (keras.backend.ctc_batch_cost, full lengths).
// B=512, T=512, C=96 (blank=95), L=64, S=2L+1=129.
//
// One 64-lane wave per batch item, wave-synchronous (no barriers).
// Linear-domain forward recurrence; exact power-of-2 rescale every 8 steps,
// computed at group end and APPLIED 4 steps later (off the critical chain;
// loss = -(log(a)+e_acc*ln2) is invariant to when scales are applied).
//
// Round 5: all waits made precise by construction.
//  - R4 post-mortem: global_load_lds is modeled as an aliasing LDS write ->
//    compiler inserts s_waitcnt vmcnt(0) before dependent ds_reads, draining
//    the prefetch at every chunk boundary (~197 cyc/step observed).
//  - Now: global->register staging (12 named float4; vmcnt tracked PER
//    REGISTER, precise) then ds_write_b128 to LDS. No global_load_lds.
//  - LDS rows padded to 100 floats (400 B, 16B-aligned writes; breaks the
//    96 % 32 == 0 systematic bank alignment of label-column reads).
//  - p-values read in 16-wide bursts per 8-row group into named scalars,
//    double-buffered A/B sets: one lgkm wait per 8 steps, issued a full
//    group (~200 cyc) ahead of use.
//  - FMA-shaped chain: a1' = fma(a1p, pl_skip, (a0+a1)*pl)  (~12 cyc/step).

constexpr int Bv = 512;
constexpr int Tv = 512;
constexpr int Cv = 96;
constexpr int Lv = 64;
constexpr int BLANK = Cv - 1;        // 95
constexpr float EPSf = 1e-7f;

constexpr int ROWS = 32;             // rows per chunk
constexpr int NCH  = Tv / ROWS;      // 16 chunks
constexpr int CF   = ROWS * Cv;      // 3072 floats per chunk in global
constexpr int RS   = 100;            // padded LDS row stride (floats); 400 B
constexpr int LBUF = ROWS * RS;      // 3200 floats per LDS buffer

__device__ __forceinline__ float dpp_shr1(float x) {   // lane i <- i-1; lane0 <- 0
    return __int_as_float(
        __builtin_amdgcn_update_dpp(0, __float_as_int(x), 0x138, 0xf, 0xf, true));
}
template <int C>
__device__ __forceinline__ float dppmax(float m) {
    return fmaxf(m, __int_as_float(
        __builtin_amdgcn_update_dpp(0, __float_as_int(m), C, 0xf, 0xf, true)));
}

__global__ void __launch_bounds__(64) ctc_fwd(const int* __restrict__ y_true,
                                              const float* __restrict__ y_pred,
                                              float* __restrict__ out) {
    __shared__ float lds[2 * LBUF];                     // 25.6 KB

    const int b = blockIdx.x;
    const int l = threadIdx.x;                          // lane 0..63
    const float* __restrict__ yp = y_pred + (size_t)b * (Tv * Cv);

    const int lab   = y_true[b * Lv + l];               // label l (< 95)
    const int labm1 = __shfl_up(lab, 1);
    const bool skip = (l > 0) && (lab != labm1);

    // per-lane LDS byte offsets for the 12 staged float4 slots
    // slot i: flat float4 f = i*64+l; row = f/24; col4 = f%24
#define WA(i) ((((i)*64 + l) / 24) * 400 + (((i)*64 + l) % 24) * 16)
    const int wa0 = WA(0),  wa1 = WA(1),  wa2 = WA(2),  wa3 = WA(3);
    const int wa4 = WA(4),  wa5 = WA(5),  wa6 = WA(6),  wa7 = WA(7);
    const int wa8 = WA(8),  wa9 = WA(9), wa10 = WA(10), wa11 = WA(11);
#undef WA

    float4 G0, G1, G2, G3, G4, G5, G6, G7, G8, G9, G10, G11;   // staging regs
#define GLOAD(g) do { const float* gp_ = (g) + l * 4;                        \
    G0 = *(const float4*)(gp_ +    0); G1 = *(const float4*)(gp_ +  256);    \
    G2 = *(const float4*)(gp_ +  512); G3 = *(const float4*)(gp_ +  768);    \
    G4 = *(const float4*)(gp_ + 1024); G5 = *(const float4*)(gp_ + 1280);    \
    G6 = *(const float4*)(gp_ + 1536); G7 = *(const float4*)(gp_ + 1792);    \
    G8 = *(const float4*)(gp_ + 2048); G9 = *(const float4*)(gp_ + 2304);    \
    G10= *(const float4*)(gp_ + 2560); G11= *(const float4*)(gp_ + 2816); } while (0)
#define SWRITE(bufn) do { char* p_ = (char*)(bufn);                          \
    *(float4*)(p_ + wa0) = G0;  *(float4*)(p_ + wa1) = G1;                   \
    *(float4*)(p_ + wa2) = G2;  *(float4*)(p_ + wa3) = G3;                   \
    *(float4*)(p_ + wa4) = G4;  *(float4*)(p_ + wa5) = G5;                   \
    *(float4*)(p_ + wa6) = G6;  *(float4*)(p_ + wa7) = G7;                   \
    *(float4*)(p_ + wa8) = G8;  *(float4*)(p_ + wa9) = G9;                   \
    *(float4*)(p_ + wa10)= G10; *(float4*)(p_ + wa11)= G11; } while (0)

    // double-buffered p-value sets (named scalars only; arrays are banned)
    float AB0,AB1,AB2,AB3,AB4,AB5,AB6,AB7, AL0,AL1,AL2,AL3,AL4,AL5,AL6,AL7;
    float BB0,BB1,BB2,BB3,BB4,BB5,BB6,BB7, BL0,BL1,BL2,BL3,BL4,BL5,BL6,BL7;
#define LOAD8(P, bb, r0) do { const float* pB_ = (bb) + BLANK;               \
    const float* pL_ = (bb) + lab;                                           \
    P##B0 = pB_[((r0)+0)*RS]; P##L0 = pL_[((r0)+0)*RS];                      \
    P##B1 = pB_[((r0)+1)*RS]; P##L1 = pL_[((r0)+1)*RS];                      \
    P##B2 = pB_[((r0)+2)*RS]; P##L2 = pL_[((r0)+2)*RS];                      \
    P##B3 = pB_[((r0)+3)*RS]; P##L3 = pL_[((r0)+3)*RS];                      \
    P##B4 = pB_[((r0)+4)*RS]; P##L4 = pL_[((r0)+4)*RS];                      \
    P##B5 = pB_[((r0)+5)*RS]; P##L5 = pL_[((r0)+5)*RS];                      \
    P##B6 = pB_[((r0)+6)*RS]; P##L6 = pL_[((r0)+6)*RS];                      \
    P##B7 = pB_[((r0)+7)*RS]; P##L7 = pL_[((r0)+7)*RS]; } while (0)

    float a0, a1, a2;                  // states 2l, 2l+1, 128(lane63)
    int   e_acc = 0;
    float sc_p = 1.0f; int e_p = 0;    // pending renorm (lag-applied)

    auto step = [&](float PB, float PL) {
        float pb  = PB + EPSf;
        float pl  = PL + EPSf;
        float pls = skip ? pl : 0.0f;
        float a1p = dpp_shr1(a1);                      // alpha[2l-1]; lane0->0
        float t01 = a0 + a1;
        float na1 = fmaf(a1p, pls, t01 * pl);          // state 2l+1
        float na0 = fmaf(a1p, pb, a0 * pb);            // state 2l
        float na2 = (a2 + a1) * pb;                    // state 128 (lane63)
        a0 = na0; a1 = na1; a2 = na2;
    };
    auto rn_apply = [&]() {                            // apply 8-step-old scale
        a0 *= sc_p; a1 *= sc_p; a2 *= sc_p; e_acc += e_p;
    };
    auto rn_compute = [&]() {                          // off-chain wave max
        float m = fmaxf(fmaxf(a0, a1), a2);
        m = dppmax<0x111>(m); m = dppmax<0x112>(m); m = dppmax<0x114>(m);
        m = dppmax<0x118>(m); m = dppmax<0x142>(m); m = dppmax<0x143>(m);
        float mw = __int_as_float(__builtin_amdgcn_readlane(__float_as_int(m), 63));
        int e; (void)frexpf(mw, &e);                   // mw = f*2^e
        sc_p = ldexpf(1.0f, -e); e_p = e;              // exact pow2 scale
    };
#define GROUP8(P) do {                                                       \
    step(P##B0, P##L0); step(P##B1, P##L1); step(P##B2, P##L2);              \
    step(P##B3, P##L3); rn_apply();                                          \
    step(P##B4, P##L4); step(P##B5, P##L5); step(P##B6, P##L6);              \
    step(P##B7, P##L7); rn_compute(); } while (0)

    // ---- prologue: chunk0 -> buf0; chunk1 loads in flight; A <- rows 0-7 ----
    GLOAD(yp);
    SWRITE(lds);
    GLOAD(yp + CF);
    LOAD8(A, lds, 0);
    const bool lane0 = (l == 0);
    a0 = lane0 ? (AB0 + EPSf) : 0.0f;                  // t=0 init
    a1 = lane0 ? (AL0 + EPSf) : 0.0f;
    a2 = 0.0f;

    for (int c = 0; c < NCH; ++c) {
        float* bufB = lds + (c & 1) * LBUF;
        float* bufN = lds + ((c & 1) ^ 1) * LBUF;

        LOAD8(B, bufB, 8);                             // rows 8-15 for group1
        if (c == 0) {                                  // init + 7 steps (t=1..7)
            step(AB1, AL1); step(AB2, AL2); step(AB3, AL3); rn_apply();
            step(AB4, AL4); step(AB5, AL5); step(AB6, AL6); step(AB7, AL7);
            rn_compute();
        } else {
            GROUP8(A);                                 // rows 0-7
        }
        LOAD8(A, bufB, 16);                            // rows 16-23 for group2
        GROUP8(B);                                     // rows 8-15
        LOAD8(B, bufB, 24);                            // rows 24-31 for group3
        GROUP8(A);                                     // rows 16-23
        if (c < NCH - 1) SWRITE(bufN);                 // chunk c+1 -> other buf
        if (c < NCH - 2) GLOAD(yp + (size_t)(c + 2) * CF);  // chunk c+2 in flight
        if (c < NCH - 1) LOAD8(A, bufN, 0);            // next chunk rows 0-7
        GROUP8(B);                                     // rows 24-31
    }

    // ---- loss = -logaddexp(alpha[127], alpha[128]) (pending scale unapplied
    //      on purpose: e_acc counts exactly the applied scales) ----
    if (l == 63) {
        float sum = a1 + a2;
        out[b] = -(logf(sum) + (float)e_acc * 0.69314718055994530942f);
    }
#undef GLOAD
#undef SWRITE
#undef LOAD8
#undef GROUP8
}

extern "C" void kernel_launch(void* const* d_in, const int* in_sizes, int n_in,
                              void* d_out, int out_size, void* d_ws, size_t ws_size,
                              hipStream_t stream) {
    const int*   y_true = (const int*)d_in[0];   // [512, 64] int32
    const float* y_pred = (const float*)d_in[1]; // [512, 512, 96] fp32
    float*       out    = (float*)d_out;         // [512, 1] fp32
    (void)in_sizes; (void)n_in; (void)out_size; (void)d_ws; (void)ws_size;
    ctc_fwd<<<Bv, 64, 0, stream>>>(y_true, y_pred, out);
}